// Round 3
// baseline (337.340 us; speedup 1.0000x reference)
//
#include <hip/hip_runtime.h>

// Atom_embedding_MP: B=4, N=100000, K=16, D=6, C_IN=13, 3 layers.
// Round-5: pins + EXPLICIT VGPR BUDGET.
//  R4 post-mortem: asm "+v" pins alone made values non-rematerializable,
//  but the allocator (occupancy heuristic, no min-waves hint) kept
//  VGPR=52 and SPILLED the pinned values to scratch -> 193us (worse).
//  Fix: __launch_bounds__(256, 2) -> min 2 waves/EU -> up to 256 VGPRs.
//  Liveness is ~110 -> expect 4 waves/SIMD (pool halves at 128), zero
//  scratch, inputs loaded from global exactly ONCE per thread.
//  - loop order d->j->k: each W1 weight s_loaded once/layer, reused over 8 k.
//  - lrelu-acc:  sum += max(x,.2x)  ==  sum += .6x + .4|x|  (2 FMAs, free abs).
//  - hsum[13] pair-reduced with __shfl_xor(.,1); tail (msg/GN/pe) done
//    redundantly in both lanes (no divergence, no broadcast).

constexpr int DD  = 6;
constexpr int KK  = 16;
constexpr int CIN = 13;
constexpr float EPSV = 1e-5f;

__global__ __launch_bounds__(256, 2) void atom_mp(
    const float* __restrict__ dist,   // [P, K]
    const float* __restrict__ at,     // [P, K, D]
    const float* __restrict__ W1,     // [3, CIN, CIN]
    const float* __restrict__ b1,     // [3, CIN]
    const float* __restrict__ W2,     // [3, CIN, D]
    const float* __restrict__ b2,     // [3, D]
    const float* __restrict__ gw,     // [3, D]
    const float* __restrict__ gb,     // [3, D]
    float* __restrict__ out,          // [P, D]
    int P)
{
    int t = blockIdx.x * blockDim.x + threadIdx.x;
    int p = t >> 1;      // point index
    int h = t & 1;       // which half of the neighbors
    if (p >= P) return;

    // ---- register-resident input: 8 neighbors x 6 feats + 8 dists --------
    float a[8 * DD];   // 48 floats
    float dq[8];

    const float4* ap4 = reinterpret_cast<const float4*>(
        at + (long)p * (KK * DD) + h * (8 * DD));
    #pragma unroll
    for (int i = 0; i < 12; ++i) {
        float4 q = ap4[i];
        a[4 * i + 0] = q.x; a[4 * i + 1] = q.y;
        a[4 * i + 2] = q.z; a[4 * i + 3] = q.w;
    }
    const float4* dp4 = reinterpret_cast<const float4*>(
        dist + (long)p * KK + h * 8);
    #pragma unroll
    for (int i = 0; i < 2; ++i) {
        float4 q = dp4[i];
        dq[4 * i + 0] = q.x; dq[4 * i + 1] = q.y;
        dq[4 * i + 2] = q.z; dq[4 * i + 3] = q.w;
    }

    // ---- PIN: make every loaded value non-rematerializable ---------------
    // With the VGPR budget from launch_bounds(256,2) these stay in
    // registers across all 3 layers (no scratch, no global re-read).
    #pragma unroll
    for (int i = 0; i < 8 * DD; ++i) asm volatile("" : "+v"(a[i]));
    #pragma unroll
    for (int i = 0; i < 8; ++i)      asm volatile("" : "+v"(dq[i]));

    float pe[DD] = {1.f, 1.f, 1.f, 1.f, 1.f, 1.f};

    #pragma unroll 1   // keep body in I$; each layer body ~1.2k instrs
    for (int L = 0; L < 3; ++L) {
        const float* w1  = W1 + L * CIN * CIN;
        const float* w2  = W2 + L * CIN * DD;
        const float* bb1 = b1 + L * CIN;
        const float* bb2 = b2 + L * DD;
        const float* gwp = gw + L * DD;
        const float* gbp = gb + L * DD;

        float hsum[CIN];

        #pragma unroll
        for (int d = 0; d < CIN; ++d) {
            // base_d = b1[d] + pe @ W1[0:6, d]
            float s = bb1[d];
            #pragma unroll
            for (int c = 0; c < DD; ++c)
                s = fmaf(pe[c], w1[c * CIN + d], s);

            // acc[k] over 8 neighbors; init folded into the j=0 FMA
            float w0 = w1[6 * CIN + d];
            float acc[8];
            #pragma unroll
            for (int k = 0; k < 8; ++k)
                acc[k] = fmaf(a[6 * k + 0], w0, s);
            #pragma unroll
            for (int j = 1; j < 7; ++j) {
                float w = w1[(6 + j) * CIN + d];
                #pragma unroll
                for (int k = 0; k < 8; ++k) {
                    float fv = (j < 6) ? a[6 * k + j] : dq[k];
                    acc[k] = fmaf(fv, w, acc[k]);
                }
            }
            // sum_k lrelu(acc[k]) = sum_k 0.6*acc + 0.4*|acc|
            float hs = 0.f;
            #pragma unroll
            for (int k = 0; k < 8; ++k) {
                hs = fmaf(0.6f, acc[k], hs);
                hs = fmaf(0.4f, __builtin_fabsf(acc[k]), hs);
            }
            hsum[d] = hs;
        }

        // reduce the lane pair (lanes 2i, 2i+1 hold halves of point i)
        #pragma unroll
        for (int d = 0; d < CIN; ++d)
            hsum[d] += __shfl_xor(hsum[d], 1, 64);

        // msg = hsum @ W2 + 16*b2   (both lanes, redundantly)
        float msg[DD];
        #pragma unroll
        for (int d = 0; d < DD; ++d) {
            float m = 16.f * bb2[d];
            #pragma unroll
            for (int c = 0; c < CIN; ++c)
                m = fmaf(hsum[c], w2[c * DD + d], m);
            msg[d] = m;
        }

        // GroupNorm(2 groups of 3) + affine + lrelu, residual add
        #pragma unroll
        for (int g = 0; g < 2; ++g) {
            float m0 = msg[3 * g], m1 = msg[3 * g + 1], m2 = msg[3 * g + 2];
            float mu = (m0 + m1 + m2) * (1.f / 3.f);
            float d0 = m0 - mu, d1 = m1 - mu, d2 = m2 - mu;
            float var = (d0 * d0 + d1 * d1 + d2 * d2) * (1.f / 3.f);
            float rs = rsqrtf(var + EPSV);
            float dv[3] = {d0, d1, d2};
            #pragma unroll
            for (int c = 0; c < 3; ++c) {
                int ch = 3 * g + c;
                float xn = fmaf(dv[c] * rs, gwp[ch], gbp[ch]);
                pe[ch] = fmaf(0.6f, xn, pe[ch]);
                pe[ch] = fmaf(0.4f, __builtin_fabsf(xn), pe[ch]);
            }
        }
    }

    // both lanes hold identical pe; split the 6-float store across the pair
    float* op = out + (long)p * DD;
    if (h == 0) {
        *reinterpret_cast<float2*>(op)     = make_float2(pe[0], pe[1]);
        *reinterpret_cast<float2*>(op + 2) = make_float2(pe[2], pe[3]);
    } else {
        *reinterpret_cast<float2*>(op + 4) = make_float2(pe[4], pe[5]);
    }
}

extern "C" void kernel_launch(void* const* d_in, const int* in_sizes, int n_in,
                              void* d_out, int out_size, void* d_ws, size_t ws_size,
                              hipStream_t stream) {
    const float* dist = (const float*)d_in[0];
    const float* at   = (const float*)d_in[1];
    const float* W1   = (const float*)d_in[2];
    const float* b1   = (const float*)d_in[3];
    const float* W2   = (const float*)d_in[4];
    const float* b2   = (const float*)d_in[5];
    const float* gw   = (const float*)d_in[6];
    const float* gb   = (const float*)d_in[7];
    float* out = (float*)d_out;

    int P = in_sizes[0] / KK;   // dist is [P, K]
    long threads_total = 2L * P;
    int threads = 256;
    int blocks = (int)((threads_total + threads - 1) / threads);
    atom_mp<<<blocks, threads, 0, stream>>>(dist, at, W1, b1, W2, b2, gw, gb, out, P);
}

// Round 4
// 278.018 us; speedup vs baseline: 1.2134x; 1.2134x over previous
//
#include <hip/hip_runtime.h>

// Atom_embedding_MP: B=4, N=100000, K=16, D=6, C_IN=13, 3 layers.
// Round-6: LDS-staged inputs + k-outer loop (low register liveness).
//  R4/R5 post-mortem: the allocator refuses to keep 56 input floats live
//  across the layer loop (pins -> scratch spills, 168-193us; no pins ->
//  per-layer L3 re-read, 102.7us @ real-VALU ~36%).
//  Fix: stop needing 56 live regs at all.
//   - Each thread stages its 48 atom feats to LDS ONCE ([feat][tid]
//     transposed: stride-256 dwords -> conflict-free; thread-private ->
//     no __syncthreads anywhere).
//   - k-outer loop: per neighbor, 6 LDS b32 reads + 91 FMA. Peak liveness
//     ~70 VGPR (base[13]+hs1[13]+hs2[13]+f[6]+dq[8]+pe[6]).
//   - Sum_k lrelu(x_k) = .6*Sum x + .4*Sum |x|  (lrelu-after-sum linearity;
//     |x| is a free VOP input modifier).
//   - 48KB LDS/block -> 3 blocks/CU -> up to 24 waves/CU (75%).
//  dq[8] (dist) kept in regs with a light pin; everything else streams.

constexpr int DD  = 6;
constexpr int KK  = 16;
constexpr int CIN = 13;
constexpr int TPB = 256;
constexpr float EPSV = 1e-5f;

__global__ __launch_bounds__(TPB) void atom_mp(
    const float* __restrict__ dist,   // [P, K]
    const float* __restrict__ at,     // [P, K, D]
    const float* __restrict__ W1,     // [3, CIN, CIN]
    const float* __restrict__ b1,     // [3, CIN]
    const float* __restrict__ W2,     // [3, CIN, D]
    const float* __restrict__ b2,     // [3, D]
    const float* __restrict__ gw,     // [3, D]
    const float* __restrict__ gb,     // [3, D]
    float* __restrict__ out,          // [P, D]
    int P)
{
    // [feat][tid]: 48 feats x 256 threads. Thread-private columns; lane i
    // always hits bank i%32 -> 2-way wave aliasing only (free on CDNA4).
    __shared__ float sa[48 * TPB];

    const int tid = threadIdx.x;
    const int t = blockIdx.x * TPB + tid;
    const int p = t >> 1;      // point index
    const int h = t & 1;       // which half of the neighbors
    if (p >= P) return;        // safe: no barriers in this kernel

    // ---- stage 8 neighbors x 6 feats into LDS (once) ---------------------
    const float4* ap4 = reinterpret_cast<const float4*>(
        at + (long)p * (KK * DD) + h * (8 * DD));
    #pragma unroll
    for (int i = 0; i < 12; ++i) {
        float4 q = ap4[i];
        sa[(4 * i + 0) * TPB + tid] = q.x;
        sa[(4 * i + 1) * TPB + tid] = q.y;
        sa[(4 * i + 2) * TPB + tid] = q.z;
        sa[(4 * i + 3) * TPB + tid] = q.w;
    }

    // ---- distances stay in registers (8 floats, lightly pinned) ----------
    float dq[8];
    const float4* dp4 = reinterpret_cast<const float4*>(
        dist + (long)p * KK + h * 8);
    #pragma unroll
    for (int i = 0; i < 2; ++i) {
        float4 q = dp4[i];
        dq[4 * i + 0] = q.x; dq[4 * i + 1] = q.y;
        dq[4 * i + 2] = q.z; dq[4 * i + 3] = q.w;
    }
    #pragma unroll
    for (int i = 0; i < 8; ++i) asm volatile("" : "+v"(dq[i]));

    float pe[DD] = {1.f, 1.f, 1.f, 1.f, 1.f, 1.f};

    #pragma unroll 1   // keep body in I$
    for (int L = 0; L < 3; ++L) {
        const float* w1  = W1 + L * CIN * CIN;
        const float* w2  = W2 + L * CIN * DD;
        const float* bb1 = b1 + L * CIN;
        const float* bb2 = b2 + L * DD;
        const float* gwp = gw + L * DD;
        const float* gbp = gb + L * DD;

        // base_d = b1[d] + pe @ W1[0:6, d]   (13 x 6 FMA)
        float base[CIN];
        #pragma unroll
        for (int d = 0; d < CIN; ++d) {
            float s = bb1[d];
            #pragma unroll
            for (int c = 0; c < DD; ++c)
                s = fmaf(pe[c], w1[c * CIN + d], s);
            base[d] = s;
        }

        // hs1 = sum_k x_kd,  hs2 = sum_k |x_kd|
        float hs1[CIN], hs2[CIN];
        #pragma unroll
        for (int d = 0; d < CIN; ++d) { hs1[d] = 0.f; hs2[d] = 0.f; }

        #pragma unroll
        for (int k = 0; k < 8; ++k) {
            const float f0 = sa[(6 * k + 0) * TPB + tid];
            const float f1 = sa[(6 * k + 1) * TPB + tid];
            const float f2 = sa[(6 * k + 2) * TPB + tid];
            const float f3 = sa[(6 * k + 3) * TPB + tid];
            const float f4 = sa[(6 * k + 4) * TPB + tid];
            const float f5 = sa[(6 * k + 5) * TPB + tid];
            const float fd = dq[k];
            #pragma unroll
            for (int d = 0; d < CIN; ++d) {
                float x = base[d];
                x = fmaf(f0, w1[ 6 * CIN + d], x);
                x = fmaf(f1, w1[ 7 * CIN + d], x);
                x = fmaf(f2, w1[ 8 * CIN + d], x);
                x = fmaf(f3, w1[ 9 * CIN + d], x);
                x = fmaf(f4, w1[10 * CIN + d], x);
                x = fmaf(f5, w1[11 * CIN + d], x);
                x = fmaf(fd, w1[12 * CIN + d], x);
                hs1[d] += x;
                hs2[d] += __builtin_fabsf(x);
            }
        }

        // lrelu-after-sum + pair reduction (lanes 2i, 2i+1 share point i)
        float hsum[CIN];
        #pragma unroll
        for (int d = 0; d < CIN; ++d)
            hsum[d] = fmaf(0.6f, hs1[d], 0.4f * hs2[d]);
        #pragma unroll
        for (int d = 0; d < CIN; ++d)
            hsum[d] += __shfl_xor(hsum[d], 1, 64);

        // msg = hsum @ W2 + 16*b2   (both lanes, redundantly)
        float msg[DD];
        #pragma unroll
        for (int d = 0; d < DD; ++d) {
            float m = 16.f * bb2[d];
            #pragma unroll
            for (int c = 0; c < CIN; ++c)
                m = fmaf(hsum[c], w2[c * DD + d], m);
            msg[d] = m;
        }

        // GroupNorm(2 groups of 3) + affine + lrelu, residual add
        #pragma unroll
        for (int g = 0; g < 2; ++g) {
            float m0 = msg[3 * g], m1 = msg[3 * g + 1], m2 = msg[3 * g + 2];
            float mu = (m0 + m1 + m2) * (1.f / 3.f);
            float d0 = m0 - mu, d1 = m1 - mu, d2 = m2 - mu;
            float var = (d0 * d0 + d1 * d1 + d2 * d2) * (1.f / 3.f);
            float rs = rsqrtf(var + EPSV);
            float dv[3] = {d0, d1, d2};
            #pragma unroll
            for (int c = 0; c < 3; ++c) {
                int ch = 3 * g + c;
                float xn = fmaf(dv[c] * rs, gwp[ch], gbp[ch]);
                pe[ch] = fmaf(0.6f, xn, pe[ch]);
                pe[ch] = fmaf(0.4f, __builtin_fabsf(xn), pe[ch]);
            }
        }
    }

    // both lanes hold identical pe; split the 6-float store across the pair
    float* op = out + (long)p * DD;
    if (h == 0) {
        *reinterpret_cast<float2*>(op)     = make_float2(pe[0], pe[1]);
        *reinterpret_cast<float2*>(op + 2) = make_float2(pe[2], pe[3]);
    } else {
        *reinterpret_cast<float2*>(op + 4) = make_float2(pe[4], pe[5]);
    }
}

extern "C" void kernel_launch(void* const* d_in, const int* in_sizes, int n_in,
                              void* d_out, int out_size, void* d_ws, size_t ws_size,
                              hipStream_t stream) {
    const float* dist = (const float*)d_in[0];
    const float* at   = (const float*)d_in[1];
    const float* W1   = (const float*)d_in[2];
    const float* b1   = (const float*)d_in[3];
    const float* W2   = (const float*)d_in[4];
    const float* b2   = (const float*)d_in[5];
    const float* gw   = (const float*)d_in[6];
    const float* gb   = (const float*)d_in[7];
    float* out = (float*)d_out;

    int P = in_sizes[0] / KK;   // dist is [P, K]
    long threads_total = 2L * P;
    int threads = TPB;
    int blocks = (int)((threads_total + threads - 1) / threads);
    atom_mp<<<blocks, threads, 0, stream>>>(dist, at, W1, b1, W2, b2, gw, gb, out, P);
}